// Round 1
// baseline (28423.477 us; speedup 1.0000x reference)
//
#include <hip/hip_runtime.h>
#include <hip/hip_bf16.h>

#define N_NODES 50000
#define N_EDGES 1600000
#define TILE    128

typedef __bf16 bf16x8 __attribute__((ext_vector_type(8)));
typedef float  f32x4  __attribute__((ext_vector_type(4)));

static __device__ __forceinline__ bf16x8 ld8(const __bf16* p) {
  return *reinterpret_cast<const bf16x8*>(p);
}
static __device__ __forceinline__ void st8(__bf16* p, bf16x8 v) {
  *reinterpret_cast<bf16x8*>(p) = v;
}
static __device__ __forceinline__ bf16x8 sub8(bf16x8 a, bf16x8 b) {
  bf16x8 r;
#pragma unroll
  for (int j = 0; j < 8; ++j) r[j] = (__bf16)((float)a[j] - (float)b[j]);
  return r;
}

// ---- prep: transpose weights to [n][k] bf16 (B-operand layout) ----
__global__ __launch_bounds__(256) void k_prep_w(
    const float* __restrict__ Wi, const float* __restrict__ Wu,
    const float* __restrict__ Wf,
    __bf16* __restrict__ WiT, __bf16* __restrict__ WuT, __bf16* __restrict__ WfT)
{
  int g = blockIdx.x * 256 + threadIdx.x;
  if (g < 160 * 128) {
    int n = g / 160, k = g % 160;
    WiT[g] = (__bf16)Wi[k * 128 + n];
  } else if (g < 160 * 128 + 128 * 128) {
    int gg = g - 160 * 128;
    int n = gg / 128, k = gg % 128;
    WuT[gg] = (__bf16)Wu[k * 128 + n];
  } else if (g < 160 * 128 + 128 * 128 + 256 * 128) {
    int gg = g - (160 * 128 + 128 * 128);
    int n = gg / 256, k = gg % 256;
    WfT[gg] = (__bf16)Wf[k * 128 + n];
  }
}

// ---- f32 -> bf16 bulk convert (used for node_feature and agg tables) ----
__global__ __launch_bounds__(256) void k_cvt(
    const float* __restrict__ in, __bf16* __restrict__ out, long n)
{
  long i = ((long)blockIdx.x * 256 + threadIdx.x) * 8;
  if (i + 8 <= n) {
    f32x4 f0 = *(const f32x4*)(in + i);
    f32x4 f1 = *(const f32x4*)(in + i + 4);
    bf16x8 o;
#pragma unroll
    for (int j = 0; j < 4; ++j) { o[j] = (__bf16)f0[j]; o[4 + j] = (__bf16)f1[j]; }
    st8(out + i, o);
  }
}

// ---- init: h0 = relu([nf[src] | ef] @ Wi + bi); scatter h0 into aggf ----
__global__ __launch_bounds__(256) void k_init(
    const __bf16* __restrict__ nfbf, const float* __restrict__ ef,
    const int* __restrict__ esrc, const int* __restrict__ edst,
    const __bf16* __restrict__ WiT, const float* __restrict__ bi,
    __bf16* __restrict__ h, float* __restrict__ aggf)
{
  __shared__ __bf16 lds[128 * 136];  // +8 elem pad breaks 256B-stride bank conflicts
  const int tid = threadIdx.x;
  const int lane = tid & 63, wave = tid >> 6;
  const int l15 = lane & 15, quad = lane >> 4;
  const int wm = wave >> 1, wn = wave & 1;
  const long base = (long)blockIdx.x * TILE;

  int srcn[4];
#pragma unroll
  for (int ms = 0; ms < 4; ++ms)
    srcn[ms] = esrc[base + wm * 64 + ms * 16 + l15];

  f32x4 acc[4][4] = {};
#pragma unroll
  for (int kit = 0; kit < 5; ++kit) {
    const int koff = kit * 32 + quad * 8;
    bf16x8 a[4];
#pragma unroll
    for (int ms = 0; ms < 4; ++ms) {
      if (kit < 4) {
        a[ms] = ld8(nfbf + (long)srcn[ms] * 128 + koff);
      } else {
        const float* p = ef + (base + wm * 64 + ms * 16 + l15) * 32 + quad * 8;
        f32x4 f0 = *(const f32x4*)p;
        f32x4 f1 = *(const f32x4*)(p + 4);
        bf16x8 v;
#pragma unroll
        for (int j = 0; j < 4; ++j) { v[j] = (__bf16)f0[j]; v[4 + j] = (__bf16)f1[j]; }
        a[ms] = v;
      }
    }
#pragma unroll
    for (int ns = 0; ns < 4; ++ns) {
      bf16x8 b = ld8(WiT + (wn * 64 + ns * 16 + l15) * 160 + koff);
#pragma unroll
      for (int ms = 0; ms < 4; ++ms)
        acc[ms][ns] = __builtin_amdgcn_mfma_f32_16x16x32_bf16(a[ms], b, acc[ms][ns], 0, 0, 0);
    }
  }
  // epilogue: relu(acc+bi) -> LDS (bf16), then coalesced store + atomic scatter
#pragma unroll
  for (int ns = 0; ns < 4; ++ns) {
    const int col = wn * 64 + ns * 16 + l15;
    const float bias = bi[col];
#pragma unroll
    for (int ms = 0; ms < 4; ++ms) {
      const int r0 = wm * 64 + ms * 16 + quad * 4;
#pragma unroll
      for (int r = 0; r < 4; ++r) {
        float v = acc[ms][ns][r] + bias;
        v = v > 0.f ? v : 0.f;
        lds[(r0 + r) * 136 + col] = (__bf16)v;
      }
    }
  }
  __syncthreads();
#pragma unroll
  for (int i = 0; i < 8; ++i) {
    const int c = i * 256 + tid;
    const int row = c >> 4, k8 = (c & 15) * 8;
    bf16x8 cv = ld8(lds + row * 136 + k8);
    const int dn = edst[base + row];
    st8(h + (base + row) * 128 + k8, cv);
#pragma unroll
    for (int j = 0; j < 8; ++j)
      unsafeAtomicAdd(aggf + (long)dn * 128 + k8 + j, (float)cv[j]);
  }
}

// ---- update: h = relu((agg[src]-h[rev]) @ Wu + bu + h); scatter h_new -> aggf ----
__global__ __launch_bounds__(256) void k_update(
    const __bf16* __restrict__ aggbf, float* __restrict__ aggf,
    __bf16* __restrict__ h,
    const int* __restrict__ esrc, const int* __restrict__ edst,
    const __bf16* __restrict__ WuT, const float* __restrict__ bu)
{
  __shared__ __bf16 lds[128 * 136];
  const int tid = threadIdx.x;
  const int lane = tid & 63, wave = tid >> 6;
  const int l15 = lane & 15, quad = lane >> 4;
  const int wm = wave >> 1, wn = wave & 1;
  const long base = (long)blockIdx.x * TILE;

  int srcn[4], rowh[4];
#pragma unroll
  for (int ms = 0; ms < 4; ++ms) {
    const int rm = wm * 64 + ms * 16 + l15;
    srcn[ms] = esrc[base + rm];
    rowh[ms] = rm ^ 1;  // rev(e) = e^1 stays inside the pair-aligned tile
  }

  f32x4 acc[4][4] = {};
#pragma unroll
  for (int kit = 0; kit < 4; ++kit) {
    const int koff = kit * 32 + quad * 8;
    bf16x8 a[4];
#pragma unroll
    for (int ms = 0; ms < 4; ++ms)
      a[ms] = sub8(ld8(aggbf + (long)srcn[ms] * 128 + koff),
                   ld8(h + (base + rowh[ms]) * 128 + koff));
#pragma unroll
    for (int ns = 0; ns < 4; ++ns) {
      bf16x8 b = ld8(WuT + (wn * 64 + ns * 16 + l15) * 128 + koff);
#pragma unroll
      for (int ms = 0; ms < 4; ++ms)
        acc[ms][ns] = __builtin_amdgcn_mfma_f32_16x16x32_bf16(a[ms], b, acc[ms][ns], 0, 0, 0);
    }
  }
  // acc + bu -> LDS (residual+relu added after roundtrip)
#pragma unroll
  for (int ns = 0; ns < 4; ++ns) {
    const int col = wn * 64 + ns * 16 + l15;
    const float bias = bu[col];
#pragma unroll
    for (int ms = 0; ms < 4; ++ms) {
      const int r0 = wm * 64 + ms * 16 + quad * 4;
#pragma unroll
      for (int r = 0; r < 4; ++r)
        lds[(r0 + r) * 136 + col] = (__bf16)(acc[ms][ns][r] + bias);
    }
  }
  __syncthreads();
#pragma unroll
  for (int i = 0; i < 8; ++i) {
    const int c = i * 256 + tid;
    const int row = c >> 4, k8 = (c & 15) * 8;
    bf16x8 cv = ld8(lds + row * 136 + k8);
    bf16x8 hv = ld8(h + (base + row) * 128 + k8);
    const int dn = edst[base + row];
    bf16x8 o;
#pragma unroll
    for (int j = 0; j < 8; ++j) {
      float v = (float)cv[j] + (float)hv[j];
      v = v > 0.f ? v : 0.f;
      o[j] = (__bf16)v;
    }
    st8(h + (base + row) * 128 + k8, o);  // in-place: only this thread touches this chunk
#pragma unroll
    for (int j = 0; j < 8; ++j)
      unsafeAtomicAdd(aggf + (long)dn * 128 + k8 + j, (float)o[j]);
  }
}

// ---- final: out = relu([nf | agg(h4)] @ Wf + bf) over nodes ----
__global__ __launch_bounds__(256) void k_final(
    const __bf16* __restrict__ nfbf, const __bf16* __restrict__ aggbf,
    const __bf16* __restrict__ WfT, const float* __restrict__ bfb,
    float* __restrict__ out)
{
  const int tid = threadIdx.x;
  const int lane = tid & 63, wave = tid >> 6;
  const int l15 = lane & 15, quad = lane >> 4;
  const int wm = wave >> 1, wn = wave & 1;
  const int base = blockIdx.x * TILE;

  int nodem[4];
#pragma unroll
  for (int ms = 0; ms < 4; ++ms) {
    int nd = base + wm * 64 + ms * 16 + l15;
    nodem[ms] = nd < N_NODES ? nd : (N_NODES - 1);
  }
  f32x4 acc[4][4] = {};
#pragma unroll
  for (int kit = 0; kit < 8; ++kit) {
    const int koff = kit * 32 + quad * 8;
    bf16x8 a[4];
#pragma unroll
    for (int ms = 0; ms < 4; ++ms)
      a[ms] = (kit < 4) ? ld8(nfbf + (long)nodem[ms] * 128 + koff)
                        : ld8(aggbf + (long)nodem[ms] * 128 + (koff - 128));
#pragma unroll
    for (int ns = 0; ns < 4; ++ns) {
      bf16x8 b = ld8(WfT + (wn * 64 + ns * 16 + l15) * 256 + koff);
#pragma unroll
      for (int ms = 0; ms < 4; ++ms)
        acc[ms][ns] = __builtin_amdgcn_mfma_f32_16x16x32_bf16(a[ms], b, acc[ms][ns], 0, 0, 0);
    }
  }
#pragma unroll
  for (int ns = 0; ns < 4; ++ns) {
    const int col = wn * 64 + ns * 16 + l15;
    const float bias = bfb[col];
#pragma unroll
    for (int ms = 0; ms < 4; ++ms) {
      const int r0 = wm * 64 + ms * 16 + quad * 4;
#pragma unroll
      for (int r = 0; r < 4; ++r) {
        const int node = base + r0 + r;
        if (node < N_NODES) {
          float v = acc[ms][ns][r] + bias;
          out[(long)node * 128 + col] = v > 0.f ? v : 0.f;
        }
      }
    }
  }
}

extern "C" void kernel_launch(void* const* d_in, const int* in_sizes, int n_in,
                              void* d_out, int out_size, void* d_ws, size_t ws_size,
                              hipStream_t stream) {
  const float* nf   = (const float*)d_in[0];
  const float* ef   = (const float*)d_in[1];
  const int*   esrc = (const int*)d_in[2];
  const int*   edst = (const int*)d_in[3];
  const float* Wi   = (const float*)d_in[4];
  const float* bi   = (const float*)d_in[5];
  const float* Wu   = (const float*)d_in[6];
  const float* bu   = (const float*)d_in[7];
  const float* Wf   = (const float*)d_in[8];
  const float* bfb  = (const float*)d_in[9];
  float* out = (float*)d_out;

  char* ws = (char*)d_ws;
  __bf16* h     = (__bf16*)(ws);                  // 1.6M*128*2  = 409,600,000 B
  float*  aggf  = (float*)(ws + 409600000L);      // 50000*128*4 =  25,600,000 B
  __bf16* aggbf = (__bf16*)(ws + 435200000L);     // 50000*128*2 =  12,800,000 B
  __bf16* nfbf  = (__bf16*)(ws + 448000000L);     // 50000*128*2 =  12,800,000 B
  __bf16* WiT   = (__bf16*)(ws + 460800000L);     // 40,960 B
  __bf16* WuT   = (__bf16*)(ws + 460840960L);     // 32,768 B
  __bf16* WfT   = (__bf16*)(ws + 460873728L);     // 65,536 B

  const long NV = (long)N_NODES * 128;

  hipLaunchKernelGGL(k_prep_w, dim3(272), dim3(256), 0, stream, Wi, Wu, Wf, WiT, WuT, WfT);
  hipLaunchKernelGGL(k_cvt, dim3(3125), dim3(256), 0, stream, nf, nfbf, NV);
  hipMemsetAsync(aggf, 0, 25600000, stream);
  hipLaunchKernelGGL(k_init, dim3(N_EDGES / TILE), dim3(256), 0, stream,
                     nfbf, ef, esrc, edst, WiT, bi, h, aggf);
  for (int t = 0; t < 4; ++t) {
    hipLaunchKernelGGL(k_cvt, dim3(3125), dim3(256), 0, stream, aggf, aggbf, NV);
    hipMemsetAsync(aggf, 0, 25600000, stream);
    hipLaunchKernelGGL(k_update, dim3(N_EDGES / TILE), dim3(256), 0, stream,
                       aggbf, aggf, h, esrc, edst, WuT, bu);
  }
  hipLaunchKernelGGL(k_cvt, dim3(3125), dim3(256), 0, stream, aggf, aggbf, NV);
  hipLaunchKernelGGL(k_final, dim3((N_NODES + TILE - 1) / TILE), dim3(256), 0, stream,
                     nfbf, aggbf, WfT, bfb, out);
}

// Round 2
// 3006.857 us; speedup vs baseline: 9.4529x; 9.4529x over previous
//
#include <hip/hip_runtime.h>
#include <hip/hip_bf16.h>

#define N_NODES 50000
#define N_EDGES 1600000
#define TILE    128

typedef __bf16 bf16x8 __attribute__((ext_vector_type(8)));
typedef __bf16 bf16x2 __attribute__((ext_vector_type(2)));
typedef float  f32x4  __attribute__((ext_vector_type(4)));

static __device__ __forceinline__ bf16x8 ld8(const __bf16* p) {
  return *reinterpret_cast<const bf16x8*>(p);
}
static __device__ __forceinline__ void st8(__bf16* p, bf16x8 v) {
  *reinterpret_cast<bf16x8*>(p) = v;
}
static __device__ __forceinline__ bf16x8 sub8(bf16x8 a, bf16x8 b) {
  bf16x8 r;
#pragma unroll
  for (int j = 0; j < 8; ++j) r[j] = (__bf16)((float)a[j] - (float)b[j]);
  return r;
}

// ---- prep: transpose weights to [n][k] bf16 (B-operand layout) ----
__global__ __launch_bounds__(256) void k_prep_w(
    const float* __restrict__ Wi, const float* __restrict__ Wu,
    const float* __restrict__ Wf,
    __bf16* __restrict__ WiT, __bf16* __restrict__ WuT, __bf16* __restrict__ WfT)
{
  int g = blockIdx.x * 256 + threadIdx.x;
  if (g < 160 * 128) {
    int n = g / 160, k = g % 160;
    WiT[g] = (__bf16)Wi[k * 128 + n];
  } else if (g < 160 * 128 + 128 * 128) {
    int gg = g - 160 * 128;
    int n = gg / 128, k = gg % 128;
    WuT[gg] = (__bf16)Wu[k * 128 + n];
  } else if (g < 160 * 128 + 128 * 128 + 256 * 128) {
    int gg = g - (160 * 128 + 128 * 128);
    int n = gg / 256, k = gg % 256;
    WfT[gg] = (__bf16)Wf[k * 128 + n];
  }
}

// ---- f32 -> bf16 bulk convert (node_feature) ----
__global__ __launch_bounds__(256) void k_cvt(
    const float* __restrict__ in, __bf16* __restrict__ out, long n)
{
  long i = ((long)blockIdx.x * 256 + threadIdx.x) * 8;
  if (i + 8 <= n) {
    f32x4 f0 = *(const f32x4*)(in + i);
    f32x4 f1 = *(const f32x4*)(in + i + 4);
    bf16x8 o;
#pragma unroll
    for (int j = 0; j < 4; ++j) { o[j] = (__bf16)f0[j]; o[4 + j] = (__bf16)f1[j]; }
    st8(out + i, o);
  }
}

// ---- CSR build: histogram of edge_dst ----
__global__ __launch_bounds__(256) void k_hist(
    const int* __restrict__ edst, int* __restrict__ cnt)
{
  int e = blockIdx.x * 256 + threadIdx.x;
  if (e < N_EDGES) atomicAdd(&cnt[edst[e]], 1);
}

// ---- CSR build: single-block exclusive scan over 50000 counters ----
__global__ __launch_bounds__(1024) void k_scan(
    const int* __restrict__ cnt, int* __restrict__ rowptr,
    int* __restrict__ cursor, int n)
{
  __shared__ int smem[1024];
  __shared__ int carry_s;
  const int tid = threadIdx.x;
  if (tid == 0) carry_s = 0;
  __syncthreads();
  for (int base = 0; base < n; base += 1024) {
    int i = base + tid;
    int v = (i < n) ? cnt[i] : 0;
    smem[tid] = v;
    __syncthreads();
    for (int off = 1; off < 1024; off <<= 1) {
      int t = (tid >= off) ? smem[tid - off] : 0;
      __syncthreads();
      smem[tid] += t;
      __syncthreads();
    }
    int carry = carry_s;
    int excl = carry + smem[tid] - v;
    if (i < n) { rowptr[i] = excl; cursor[i] = excl; }
    int total = smem[1023];
    __syncthreads();
    if (tid == 0) carry_s = carry + total;
    __syncthreads();
  }
  if (tid == 0) rowptr[n] = carry_s;
}

// ---- CSR build: fill incoming-edge lists ----
__global__ __launch_bounds__(256) void k_fill(
    const int* __restrict__ edst, int* __restrict__ cursor, int* __restrict__ eidx)
{
  int e = blockIdx.x * 256 + threadIdx.x;
  if (e < N_EDGES) {
    int p = atomicAdd(&cursor[edst[e]], 1);
    eidx[p] = e;
  }
}

// ---- gather-aggregate: aggbf[n] = sum over incoming edges h[e] ----
__global__ __launch_bounds__(256) void k_agg(
    const __bf16* __restrict__ h, const int* __restrict__ rowptr,
    const int* __restrict__ eidx, __bf16* __restrict__ aggbf)
{
  const int node = blockIdx.x * 4 + (threadIdx.x >> 6);
  if (node >= N_NODES) return;
  const int lane = threadIdx.x & 63;
  const int s = rowptr[node], e = rowptr[node + 1];
  float a0 = 0.f, a1 = 0.f;
  int i = s;
  for (; i + 4 <= e; i += 4) {
    int e0 = eidx[i], e1 = eidx[i + 1], e2 = eidx[i + 2], e3 = eidx[i + 3];
    bf16x2 v0 = *(const bf16x2*)(h + (long)e0 * 128 + lane * 2);
    bf16x2 v1 = *(const bf16x2*)(h + (long)e1 * 128 + lane * 2);
    bf16x2 v2 = *(const bf16x2*)(h + (long)e2 * 128 + lane * 2);
    bf16x2 v3 = *(const bf16x2*)(h + (long)e3 * 128 + lane * 2);
    a0 += (float)v0[0] + (float)v1[0] + (float)v2[0] + (float)v3[0];
    a1 += (float)v0[1] + (float)v1[1] + (float)v2[1] + (float)v3[1];
  }
  for (; i < e; ++i) {
    int e0 = eidx[i];
    bf16x2 v0 = *(const bf16x2*)(h + (long)e0 * 128 + lane * 2);
    a0 += (float)v0[0];
    a1 += (float)v0[1];
  }
  bf16x2 o; o[0] = (__bf16)a0; o[1] = (__bf16)a1;
  *(bf16x2*)(aggbf + (long)node * 128 + lane * 2) = o;
}

// ---- init: h0 = relu([nf[src] | ef] @ Wi + bi) ----
__global__ __launch_bounds__(256) void k_init(
    const __bf16* __restrict__ nfbf, const float* __restrict__ ef,
    const int* __restrict__ esrc,
    const __bf16* __restrict__ WiT, const float* __restrict__ bi,
    __bf16* __restrict__ h)
{
  __shared__ __bf16 lds[128 * 136];  // +8 elem pad breaks 256B-stride bank conflicts
  const int tid = threadIdx.x;
  const int lane = tid & 63, wave = tid >> 6;
  const int l15 = lane & 15, quad = lane >> 4;
  const int wm = wave >> 1, wn = wave & 1;
  const long base = (long)blockIdx.x * TILE;

  int srcn[4];
#pragma unroll
  for (int ms = 0; ms < 4; ++ms)
    srcn[ms] = esrc[base + wm * 64 + ms * 16 + l15];

  f32x4 acc[4][4] = {};
#pragma unroll
  for (int kit = 0; kit < 5; ++kit) {
    const int koff = kit * 32 + quad * 8;
    bf16x8 a[4];
#pragma unroll
    for (int ms = 0; ms < 4; ++ms) {
      if (kit < 4) {
        a[ms] = ld8(nfbf + (long)srcn[ms] * 128 + koff);
      } else {
        const float* p = ef + (base + wm * 64 + ms * 16 + l15) * 32 + quad * 8;
        f32x4 f0 = *(const f32x4*)p;
        f32x4 f1 = *(const f32x4*)(p + 4);
        bf16x8 v;
#pragma unroll
        for (int j = 0; j < 4; ++j) { v[j] = (__bf16)f0[j]; v[4 + j] = (__bf16)f1[j]; }
        a[ms] = v;
      }
    }
#pragma unroll
    for (int ns = 0; ns < 4; ++ns) {
      bf16x8 b = ld8(WiT + (wn * 64 + ns * 16 + l15) * 160 + koff);
#pragma unroll
      for (int ms = 0; ms < 4; ++ms)
        acc[ms][ns] = __builtin_amdgcn_mfma_f32_16x16x32_bf16(a[ms], b, acc[ms][ns], 0, 0, 0);
    }
  }
#pragma unroll
  for (int ns = 0; ns < 4; ++ns) {
    const int col = wn * 64 + ns * 16 + l15;
    const float bias = bi[col];
#pragma unroll
    for (int ms = 0; ms < 4; ++ms) {
      const int r0 = wm * 64 + ms * 16 + quad * 4;
#pragma unroll
      for (int r = 0; r < 4; ++r) {
        float v = acc[ms][ns][r] + bias;
        v = v > 0.f ? v : 0.f;
        lds[(r0 + r) * 136 + col] = (__bf16)v;
      }
    }
  }
  __syncthreads();
#pragma unroll
  for (int i = 0; i < 8; ++i) {
    const int c = i * 256 + tid;
    const int row = c >> 4, k8 = (c & 15) * 8;
    st8(h + (base + row) * 128 + k8, ld8(lds + row * 136 + k8));
  }
}

// ---- update: h = relu((agg[src]-h[rev]) @ Wu + bu + h) ----
__global__ __launch_bounds__(256) void k_update(
    const __bf16* __restrict__ aggbf, __bf16* __restrict__ h,
    const int* __restrict__ esrc,
    const __bf16* __restrict__ WuT, const float* __restrict__ bu)
{
  __shared__ __bf16 lds[128 * 136];
  const int tid = threadIdx.x;
  const int lane = tid & 63, wave = tid >> 6;
  const int l15 = lane & 15, quad = lane >> 4;
  const int wm = wave >> 1, wn = wave & 1;
  const long base = (long)blockIdx.x * TILE;

  int srcn[4], rowh[4];
#pragma unroll
  for (int ms = 0; ms < 4; ++ms) {
    const int rm = wm * 64 + ms * 16 + l15;
    srcn[ms] = esrc[base + rm];
    rowh[ms] = rm ^ 1;  // rev(e) = e^1 stays inside the pair-aligned tile
  }

  f32x4 acc[4][4] = {};
#pragma unroll
  for (int kit = 0; kit < 4; ++kit) {
    const int koff = kit * 32 + quad * 8;
    bf16x8 a[4];
#pragma unroll
    for (int ms = 0; ms < 4; ++ms)
      a[ms] = sub8(ld8(aggbf + (long)srcn[ms] * 128 + koff),
                   ld8(h + (base + rowh[ms]) * 128 + koff));
#pragma unroll
    for (int ns = 0; ns < 4; ++ns) {
      bf16x8 b = ld8(WuT + (wn * 64 + ns * 16 + l15) * 128 + koff);
#pragma unroll
      for (int ms = 0; ms < 4; ++ms)
        acc[ms][ns] = __builtin_amdgcn_mfma_f32_16x16x32_bf16(a[ms], b, acc[ms][ns], 0, 0, 0);
    }
  }
#pragma unroll
  for (int ns = 0; ns < 4; ++ns) {
    const int col = wn * 64 + ns * 16 + l15;
    const float bias = bu[col];
#pragma unroll
    for (int ms = 0; ms < 4; ++ms) {
      const int r0 = wm * 64 + ms * 16 + quad * 4;
#pragma unroll
      for (int r = 0; r < 4; ++r)
        lds[(r0 + r) * 136 + col] = (__bf16)(acc[ms][ns][r] + bias);
    }
  }
  __syncthreads();
#pragma unroll
  for (int i = 0; i < 8; ++i) {
    const int c = i * 256 + tid;
    const int row = c >> 4, k8 = (c & 15) * 8;
    bf16x8 cv = ld8(lds + row * 136 + k8);
    bf16x8 hv = ld8(h + (base + row) * 128 + k8);
    bf16x8 o;
#pragma unroll
    for (int j = 0; j < 8; ++j) {
      float v = (float)cv[j] + (float)hv[j];
      v = v > 0.f ? v : 0.f;
      o[j] = (__bf16)v;
    }
    st8(h + (base + row) * 128 + k8, o);  // in-place: only this thread touches this chunk
  }
}

// ---- final: out = relu([nf | agg(h4)] @ Wf + bf) over nodes ----
__global__ __launch_bounds__(256) void k_final(
    const __bf16* __restrict__ nfbf, const __bf16* __restrict__ aggbf,
    const __bf16* __restrict__ WfT, const float* __restrict__ bfb,
    float* __restrict__ out)
{
  const int tid = threadIdx.x;
  const int lane = tid & 63, wave = tid >> 6;
  const int l15 = lane & 15, quad = lane >> 4;
  const int wm = wave >> 1, wn = wave & 1;
  const int base = blockIdx.x * TILE;

  int nodem[4];
#pragma unroll
  for (int ms = 0; ms < 4; ++ms) {
    int nd = base + wm * 64 + ms * 16 + l15;
    nodem[ms] = nd < N_NODES ? nd : (N_NODES - 1);
  }
  f32x4 acc[4][4] = {};
#pragma unroll
  for (int kit = 0; kit < 8; ++kit) {
    const int koff = kit * 32 + quad * 8;
    bf16x8 a[4];
#pragma unroll
    for (int ms = 0; ms < 4; ++ms)
      a[ms] = (kit < 4) ? ld8(nfbf + (long)nodem[ms] * 128 + koff)
                        : ld8(aggbf + (long)nodem[ms] * 128 + (koff - 128));
#pragma unroll
    for (int ns = 0; ns < 4; ++ns) {
      bf16x8 b = ld8(WfT + (wn * 64 + ns * 16 + l15) * 256 + koff);
#pragma unroll
      for (int ms = 0; ms < 4; ++ms)
        acc[ms][ns] = __builtin_amdgcn_mfma_f32_16x16x32_bf16(a[ms], b, acc[ms][ns], 0, 0, 0);
    }
  }
#pragma unroll
  for (int ns = 0; ns < 4; ++ns) {
    const int col = wn * 64 + ns * 16 + l15;
    const float bias = bfb[col];
#pragma unroll
    for (int ms = 0; ms < 4; ++ms) {
      const int r0 = wm * 64 + ms * 16 + quad * 4;
#pragma unroll
      for (int r = 0; r < 4; ++r) {
        const int node = base + r0 + r;
        if (node < N_NODES) {
          float v = acc[ms][ns][r] + bias;
          out[(long)node * 128 + col] = v > 0.f ? v : 0.f;
        }
      }
    }
  }
}

extern "C" void kernel_launch(void* const* d_in, const int* in_sizes, int n_in,
                              void* d_out, int out_size, void* d_ws, size_t ws_size,
                              hipStream_t stream) {
  const float* nf   = (const float*)d_in[0];
  const float* ef   = (const float*)d_in[1];
  const int*   esrc = (const int*)d_in[2];
  const int*   edst = (const int*)d_in[3];
  const float* Wi   = (const float*)d_in[4];
  const float* bi   = (const float*)d_in[5];
  const float* Wu   = (const float*)d_in[6];
  const float* bu   = (const float*)d_in[7];
  const float* Wf   = (const float*)d_in[8];
  const float* bfb  = (const float*)d_in[9];
  float* out = (float*)d_out;

  char* ws = (char*)d_ws;
  __bf16* h      = (__bf16*)(ws);                  // 409,600,000 B
  __bf16* aggbf  = (__bf16*)(ws + 409600000L);     //  12,800,000 B
  __bf16* nfbf   = (__bf16*)(ws + 422400000L);     //  12,800,000 B
  __bf16* WiT    = (__bf16*)(ws + 435200000L);     //      40,960 B
  __bf16* WuT    = (__bf16*)(ws + 435240960L);     //      32,768 B
  __bf16* WfT    = (__bf16*)(ws + 435273728L);     //      65,536 B
  int*    cnt    = (int*)(ws + 435339264L);        //     200,000 B
  int*    rowptr = (int*)(ws + 435539264L);        //     200,064 B (50001 ints)
  int*    cursor = (int*)(ws + 435739328L);        //     200,000 B
  int*    eidx   = (int*)(ws + 435939328L);        //   6,400,000 B

  const long NV = (long)N_NODES * 128;

  hipLaunchKernelGGL(k_prep_w, dim3(272), dim3(256), 0, stream, Wi, Wu, Wf, WiT, WuT, WfT);
  hipLaunchKernelGGL(k_cvt, dim3(3125), dim3(256), 0, stream, nf, nfbf, NV);
  // CSR build (edge_dst -> incoming edge lists)
  hipMemsetAsync(cnt, 0, 200000, stream);
  hipLaunchKernelGGL(k_hist, dim3(N_EDGES / 256), dim3(256), 0, stream, edst, cnt);
  hipLaunchKernelGGL(k_scan, dim3(1), dim3(1024), 0, stream, cnt, rowptr, cursor, N_NODES);
  hipLaunchKernelGGL(k_fill, dim3(N_EDGES / 256), dim3(256), 0, stream, edst, cursor, eidx);

  hipLaunchKernelGGL(k_init, dim3(N_EDGES / TILE), dim3(256), 0, stream,
                     nfbf, ef, esrc, WiT, bi, h);
  for (int t = 0; t < 4; ++t) {
    hipLaunchKernelGGL(k_agg, dim3(N_NODES / 4), dim3(256), 0, stream, h, rowptr, eidx, aggbf);
    hipLaunchKernelGGL(k_update, dim3(N_EDGES / TILE), dim3(256), 0, stream,
                       aggbf, h, esrc, WuT, bu);
  }
  hipLaunchKernelGGL(k_agg, dim3(N_NODES / 4), dim3(256), 0, stream, h, rowptr, eidx, aggbf);
  hipLaunchKernelGGL(k_final, dim3((N_NODES + TILE - 1) / TILE), dim3(256), 0, stream,
                     nfbf, aggbf, WfT, bfb, out);
}